// Round 1
// baseline (437.834 us; speedup 1.0000x reference)
//
#include <hip/hip_runtime.h>
#include <hip/hip_bf16.h>
#include <cstdint>
#include <cstddef>

// Problem constants (reference: T=4096, C=2048, NE=2048)
#define T_LEN   4096
#define C_DIM   2048
#define NE_DIM  2048
#define CHUNK   64
#define NCHUNK  (T_LEN / CHUNK)

typedef __bf16 bf16;
typedef __attribute__((ext_vector_type(8))) __bf16 bf16x8;
typedef __attribute__((ext_vector_type(4))) __bf16 bf16x4;
typedef __attribute__((ext_vector_type(4))) float  f32x4;

// ---------------------------------------------------------------------------
// async global->LDS, 16B per lane (dest must be wave-uniform-base + lane*16)
__device__ __forceinline__ void gld_lds16(bf16* lds_dst, const bf16* g_src) {
  __builtin_amdgcn_global_load_lds(
      (__attribute__((address_space(1))) void*)(g_src),
      (__attribute__((address_space(3))) void*)(lds_dst),
      16, 0, 0);
}

// ---------------------------------------------------------------------------
// Fused time-shift + mix: xk/xv/xr = x*m + shift(x)*(1-m), cast to bf16.
__global__ __launch_bounds__(256) void mix_kernel(
    const float* __restrict__ x,
    const float* __restrict__ tmk, const float* __restrict__ tmv,
    const float* __restrict__ tmr,
    bf16* __restrict__ xk, bf16* __restrict__ xv, bf16* __restrict__ xr)
{
  int gid = blockIdx.x * 256 + threadIdx.x;          // over T*NE/4
  int row = gid / (NE_DIM / 4);
  int e4  = gid % (NE_DIM / 4);
  const f32x4* x4 = (const f32x4*)x;
  f32x4 zero = {0.f, 0.f, 0.f, 0.f};
  f32x4 xc = x4[gid];
  f32x4 xp = (row > 0) ? x4[gid - NE_DIM / 4] : zero;
  f32x4 mk = ((const f32x4*)tmk)[e4];
  f32x4 mv = ((const f32x4*)tmv)[e4];
  f32x4 mr = ((const f32x4*)tmr)[e4];
  f32x4 vk = xc * mk + xp * (1.0f - mk);
  f32x4 vv = xc * mv + xp * (1.0f - mv);
  f32x4 vr = xc * mr + xp * (1.0f - mr);
  bf16x4 ok, ov, orr;
#pragma unroll
  for (int i = 0; i < 4; ++i) {
    ok[i]  = (bf16)vk[i];
    ov[i]  = (bf16)vv[i];
    orr[i] = (bf16)vr[i];
  }
  *(bf16x4*)(xk + (size_t)gid * 4) = ok;
  *(bf16x4*)(xv + (size_t)gid * 4) = ov;
  *(bf16x4*)(xr + (size_t)gid * 4) = orr;
}

// ---------------------------------------------------------------------------
// Transpose [2048x2048] f32 -> bf16 [N][K] (B^T layout for the GEMM).
__global__ __launch_bounds__(256) void wtrans(
    const float* __restrict__ W0, const float* __restrict__ W1,
    const float* __restrict__ W2, const float* __restrict__ W3,
    bf16* __restrict__ O0, bf16* __restrict__ O1,
    bf16* __restrict__ O2, bf16* __restrict__ O3)
{
  __shared__ float tile[32][33];
  int z = blockIdx.z;
  const float* W = (z == 0) ? W0 : (z == 1) ? W1 : (z == 2) ? W2 : W3;
  bf16* O        = (z == 0) ? O0 : (z == 1) ? O1 : (z == 2) ? O2 : O3;
  int bx = blockIdx.x * 32, by = blockIdx.y * 32;
  int tx = threadIdx.x, ty = threadIdx.y;
#pragma unroll
  for (int j = 0; j < 4; ++j)
    tile[ty + j * 8][tx] = W[(size_t)(by + ty + j * 8) * NE_DIM + bx + tx];
  __syncthreads();
#pragma unroll
  for (int j = 0; j < 4; ++j)
    O[(size_t)(bx + ty + j * 8) * NE_DIM + by + tx] = (bf16)tile[tx][ty + j * 8];
}

// ---------------------------------------------------------------------------
// bf16 GEMM, C[M,N] = A[M,K] @ B[K,N] with B supplied transposed (Bt=[N][K]).
// m97 structure: 128x128 tile, BK=32, 256 thr (4 waves 2x2), 16x16x32 MFMA,
// global_load_lds width-16 staging, linear LDS.
#define BM 128
#define BN 128
#define BK 32
__global__ __launch_bounds__(256) void gemm_bt(
    const bf16* __restrict__ A, const bf16* __restrict__ Bt,
    float* __restrict__ C, int M, int N, int K)
{
  __shared__ __align__(16) bf16 As[BM * BK];
  __shared__ __align__(16) bf16 Bs[BN * BK];
  int tid = threadIdx.x;
  int bm = blockIdx.y, bn = blockIdx.x;
  int w = tid >> 6, lane = tid & 63;
  int wm = w >> 1, wn = w & 1;        // 2x2 wave grid, each wave 64x64
  int lr = lane & 15, kb = lane >> 4; // frag row/col, k-block
  f32x4 acc[4][4] = {};

  const bf16* Ab = A  + (size_t)(bm * BM) * K;
  const bf16* Bb = Bt + (size_t)(bn * BN) * K;
  int s0 = tid, s1 = tid + 256;           // 16B slots (512 total per tile)
  int r0 = s0 >> 2, c0 = (s0 & 3) * 8;    // row, k-elem offset
  int r1 = s1 >> 2, c1 = (s1 & 3) * 8;

  for (int k0 = 0; k0 < K; k0 += BK) {
    gld_lds16(&As[s0 * 8], Ab + (size_t)r0 * K + k0 + c0);
    gld_lds16(&As[s1 * 8], Ab + (size_t)r1 * K + k0 + c1);
    gld_lds16(&Bs[s0 * 8], Bb + (size_t)r0 * K + k0 + c0);
    gld_lds16(&Bs[s1 * 8], Bb + (size_t)r1 * K + k0 + c1);
    __syncthreads();

    bf16x8 af[4], bfr[4];
#pragma unroll
    for (int mi = 0; mi < 4; ++mi)
      af[mi] = *(const bf16x8*)&As[(wm * 64 + mi * 16 + lr) * BK + kb * 8];
#pragma unroll
    for (int ni = 0; ni < 4; ++ni)
      bfr[ni] = *(const bf16x8*)&Bs[(wn * 64 + ni * 16 + lr) * BK + kb * 8];
#pragma unroll
    for (int mi = 0; mi < 4; ++mi)
#pragma unroll
      for (int ni = 0; ni < 4; ++ni)
        acc[mi][ni] = __builtin_amdgcn_mfma_f32_16x16x32_bf16(
            af[mi], bfr[ni], acc[mi][ni], 0, 0, 0);
    __syncthreads();
  }

#pragma unroll
  for (int mi = 0; mi < 4; ++mi)
#pragma unroll
    for (int ni = 0; ni < 4; ++ni) {
      int rbase = bm * BM + wm * 64 + mi * 16 + kb * 4;
      int col   = bn * BN + wn * 64 + ni * 16 + lr;
#pragma unroll
      for (int j = 0; j < 4; ++j)
        C[(size_t)(rbase + j) * N + col] = acc[mi][ni][j];
    }
}

// ---------------------------------------------------------------------------
// WKV chunked scan.  Per channel c: decay-per-step D = exp(-f), f = exp(-exp(td)).
// A_{t+1} = D*A_t + e^k v ; B_{t+1} = D*B_t + e^k ;
// wkv_t = (A_t + e^{u+k_t} v_t) / (B_t + e^{u+k_t})
__global__ __launch_bounds__(256) void wkv_phase1(
    const float* __restrict__ k, const float* __restrict__ v,
    const float* __restrict__ td,
    float* __restrict__ SA, float* __restrict__ SB)
{
  int c = blockIdx.x * 256 + threadIdx.x;
  int m = blockIdx.y;
  float f = __expf(-__expf(td[c]));
  float D = __expf(-f);
  float sa = 0.f, sb = 0.f;
  size_t base = (size_t)m * CHUNK * C_DIM + c;
  for (int t = 0; t < CHUNK; ++t) {
    float ek = __expf(k[base + (size_t)t * C_DIM]);
    float vv = v[base + (size_t)t * C_DIM];
    sa = D * sa + ek * vv;
    sb = D * sb + ek;
  }
  SA[(size_t)m * C_DIM + c] = sa;
  SB[(size_t)m * C_DIM + c] = sb;
}

__global__ __launch_bounds__(256) void wkv_phase2(
    const float* __restrict__ td,
    const float* __restrict__ SA, const float* __restrict__ SB,
    float* __restrict__ A0, float* __restrict__ B0)
{
  int c = blockIdx.x * 256 + threadIdx.x;
  float f  = __expf(-__expf(td[c]));
  float DL = __expf(-f * (float)CHUNK);
  float a = 0.f, b = 0.f;
  for (int m = 0; m < NCHUNK; ++m) {
    A0[(size_t)m * C_DIM + c] = a;
    B0[(size_t)m * C_DIM + c] = b;
    a = DL * a + SA[(size_t)m * C_DIM + c];
    b = DL * b + SB[(size_t)m * C_DIM + c];
  }
}

__global__ __launch_bounds__(256) void wkv_phase3(
    const float* __restrict__ k, const float* __restrict__ v,
    const float* __restrict__ r,
    const float* __restrict__ td, const float* __restrict__ tf,
    const float* __restrict__ A0, const float* __restrict__ B0,
    bf16* __restrict__ y)
{
  int c = blockIdx.x * 256 + threadIdx.x;
  int m = blockIdx.y;
  float f  = __expf(-__expf(td[c]));
  float D  = __expf(-f);
  float eu = __expf(tf[c]);
  float a = A0[(size_t)m * C_DIM + c];
  float b = B0[(size_t)m * C_DIM + c];
  size_t base = (size_t)m * CHUNK * C_DIM + c;
  for (int t = 0; t < CHUNK; ++t) {
    size_t idx = base + (size_t)t * C_DIM;
    float kk = k[idx], vv = v[idx], rr = r[idx];
    float ek  = __expf(kk);
    float euk = eu * ek;
    float wkv = (a + euk * vv) / (b + euk);
    float sr  = 1.0f / (1.0f + __expf(-rr));
    y[idx] = (bf16)(sr * wkv);
    a = D * a + ek * vv;
    b = D * b + ek;
  }
}

// ---------------------------------------------------------------------------
extern "C" void kernel_launch(void* const* d_in, const int* in_sizes, int n_in,
                              void* d_out, int out_size, void* d_ws, size_t ws_size,
                              hipStream_t stream)
{
  (void)in_sizes; (void)n_in; (void)out_size; (void)ws_size;
  const float* x   = (const float*)d_in[0];
  const float* tf  = (const float*)d_in[1];
  const float* td  = (const float*)d_in[2];
  const float* tmk = (const float*)d_in[3];
  const float* tmv = (const float*)d_in[4];
  const float* tmr = (const float*)d_in[5];
  const float* Wk  = (const float*)d_in[6];
  const float* Wv  = (const float*)d_in[7];
  const float* Wr  = (const float*)d_in[8];
  const float* Wo  = (const float*)d_in[9];
  float* out = (float*)d_out;

  char* ws = (char*)d_ws;
  size_t off = 0;
  auto alloc = [&](size_t bytes) {
    void* p = ws + off;
    off += (bytes + 255) & ~(size_t)255;
    return p;
  };
  const size_t TN  = (size_t)T_LEN * NE_DIM;   // 8,388,608
  const size_t WN  = (size_t)C_DIM * NE_DIM;   // 4,194,304

  bf16* xk  = (bf16*)alloc(TN * 2);
  bf16* xv  = (bf16*)alloc(TN * 2);
  bf16* xr  = (bf16*)alloc(TN * 2);
  bf16* WkT = (bf16*)alloc(WN * 2);
  bf16* WvT = (bf16*)alloc(WN * 2);
  bf16* WrT = (bf16*)alloc(WN * 2);
  bf16* WoT = (bf16*)alloc(WN * 2);
  float* kb = (float*)alloc(TN * 4);
  float* vb = (float*)alloc(TN * 4);
  float* rb = (float*)alloc(TN * 4);
  // Aliases into dead regions (stream-ordered; xk dead after GEMMs, xv too):
  bf16*  y  = xk;                              // [T,C] bf16, 16.8MB
  float* SA = (float*)xv;                      // 4 x 512KB into xv's 16.8MB
  float* SB = SA + (size_t)NCHUNK * C_DIM;
  float* A0 = SB + (size_t)NCHUNK * C_DIM;
  float* B0 = A0 + (size_t)NCHUNK * C_DIM;

  // 1. mix + bf16 cast
  mix_kernel<<<dim3((unsigned)(TN / 4 / 256)), 256, 0, stream>>>(
      x, tmk, tmv, tmr, xk, xv, xr);
  // 2. weight transpose + bf16 cast (all 4 via z)
  wtrans<<<dim3(64, 64, 4), dim3(32, 8), 0, stream>>>(
      Wk, Wv, Wr, Wo, WkT, WvT, WrT, WoT);
  // 3. k/v/r projections
  dim3 ggrid(NE_DIM / BN, T_LEN / BM);
  gemm_bt<<<ggrid, 256, 0, stream>>>(xk, WkT, kb, T_LEN, C_DIM, NE_DIM);
  gemm_bt<<<ggrid, 256, 0, stream>>>(xv, WvT, vb, T_LEN, C_DIM, NE_DIM);
  gemm_bt<<<ggrid, 256, 0, stream>>>(xr, WrT, rb, T_LEN, C_DIM, NE_DIM);
  // 4. WKV chunked scan + sigmoid fuse -> y (bf16)
  wkv_phase1<<<dim3(C_DIM / 256, NCHUNK), 256, 0, stream>>>(kb, vb, td, SA, SB);
  wkv_phase2<<<dim3(C_DIM / 256), 256, 0, stream>>>(td, SA, SB, A0, B0);
  wkv_phase3<<<dim3(C_DIM / 256, NCHUNK), 256, 0, stream>>>(
      kb, vb, rb, td, tf, A0, B0, y);
  // 5. output projection
  gemm_bt<<<ggrid, 256, 0, stream>>>(y, WoT, out, T_LEN, NE_DIM, C_DIM);
}

// Round 3
// 371.398 us; speedup vs baseline: 1.1789x; 1.1789x over previous
//
#include <hip/hip_runtime.h>
#include <hip/hip_bf16.h>
#include <cstdint>
#include <cstddef>

// Problem constants (reference: T=4096, C=2048, NE=2048)
#define T_LEN   4096
#define C_DIM   2048
#define NE_DIM  2048
#define CHUNK   64
#define NCHUNK  (T_LEN / CHUNK)

typedef __bf16 bf16;
typedef __attribute__((ext_vector_type(8))) __bf16 bf16x8;
typedef __attribute__((ext_vector_type(4))) __bf16 bf16x4;
typedef __attribute__((ext_vector_type(4))) float  f32x4;

// ---------------------------------------------------------------------------
// async global->LDS, 16B per lane (dest is wave-uniform base + lane*16)
__device__ __forceinline__ void gld_lds16(bf16* lds_dst, const bf16* g_src) {
  __builtin_amdgcn_global_load_lds(
      (__attribute__((address_space(1))) void*)(g_src),
      (__attribute__((address_space(3))) void*)(lds_dst),
      16, 0, 0);
}

// ---------------------------------------------------------------------------
// Fused time-shift + mix: xk/xv/xr = x*m + shift(x)*(1-m), cast to bf16.
__global__ __launch_bounds__(256) void mix_kernel(
    const float* __restrict__ x,
    const float* __restrict__ tmk, const float* __restrict__ tmv,
    const float* __restrict__ tmr,
    bf16* __restrict__ xk, bf16* __restrict__ xv, bf16* __restrict__ xr)
{
  int gid = blockIdx.x * 256 + threadIdx.x;          // over T*NE/4
  int row = gid / (NE_DIM / 4);
  int e4  = gid % (NE_DIM / 4);
  const f32x4* x4 = (const f32x4*)x;
  f32x4 zero = {0.f, 0.f, 0.f, 0.f};
  f32x4 xc = x4[gid];
  f32x4 xp = (row > 0) ? x4[gid - NE_DIM / 4] : zero;
  f32x4 mk = ((const f32x4*)tmk)[e4];
  f32x4 mv = ((const f32x4*)tmv)[e4];
  f32x4 mr = ((const f32x4*)tmr)[e4];
  f32x4 vk = xc * mk + xp * (1.0f - mk);
  f32x4 vv = xc * mv + xp * (1.0f - mv);
  f32x4 vr = xc * mr + xp * (1.0f - mr);
  bf16x4 ok, ov, orr;
#pragma unroll
  for (int i = 0; i < 4; ++i) {
    ok[i]  = (bf16)vk[i];
    ov[i]  = (bf16)vv[i];
    orr[i] = (bf16)vr[i];
  }
  *(bf16x4*)(xk + (size_t)gid * 4) = ok;
  *(bf16x4*)(xv + (size_t)gid * 4) = ov;
  *(bf16x4*)(xr + (size_t)gid * 4) = orr;
}

// ---------------------------------------------------------------------------
// Transpose [2048x2048] f32 -> bf16 [N][K] (B^T layout for the GEMM).
__global__ __launch_bounds__(256) void wtrans(
    const float* __restrict__ W0, const float* __restrict__ W1,
    const float* __restrict__ W2, const float* __restrict__ W3,
    bf16* __restrict__ O0, bf16* __restrict__ O1,
    bf16* __restrict__ O2, bf16* __restrict__ O3)
{
  __shared__ float tile[32][33];
  int z = blockIdx.z;
  const float* W = (z == 0) ? W0 : (z == 1) ? W1 : (z == 2) ? W2 : W3;
  bf16* O        = (z == 0) ? O0 : (z == 1) ? O1 : (z == 2) ? O2 : O3;
  int bx = blockIdx.x * 32, by = blockIdx.y * 32;
  int tx = threadIdx.x, ty = threadIdx.y;
#pragma unroll
  for (int j = 0; j < 4; ++j)
    tile[ty + j * 8][tx] = W[(size_t)(by + ty + j * 8) * NE_DIM + bx + tx];
  __syncthreads();
#pragma unroll
  for (int j = 0; j < 4; ++j)
    O[(size_t)(bx + ty + j * 8) * NE_DIM + by + tx] = (bf16)tile[tx][ty + j * 8];
}

// ---------------------------------------------------------------------------
// 8-phase pipelined bf16 GEMM: C[4096,2048] = A[4096,2048] @ Bt[2048,2048]^T
// BM=128, BN=256, BK=64, 512 thr (8 waves 2Mx4N, 64x64 out each).
// T1 XCD swizzle + T2 LDS XOR swizzle + T3/T4 8-phase counted vmcnt + T5 setprio.
//
// Halves: Ah0 = A rows 0-63, Ah1 = 64-127; Bh0 = B rows(cols) 0-127, Bh1 = 128-255.
// Phase quadrants (gray code): p1(Ah0,Bh0) p2(Ah1,Bh0) p3(Ah1,Bh1) p4(Ah0,Bh1),
// so one region frees per phase; stages target only freed regions.
// vmcnt(3) at p4/p8 = the 3 loads issued at p3+p4 (p7+p8) stay in flight.
#define GK 2048
#define NTILE (GK / 64)        // 32 K-tiles
#define NITER (NTILE / 2)      // 16 iterations (2 tiles each)

#define BARS() asm volatile("s_barrier" ::: "memory")
#define VMC(n) asm volatile("s_waitcnt vmcnt(" #n ")" ::: "memory")

// LDS element offsets (bf16): A buf b at b*8192 (128x64); B buf b at 16384+b*16384 (256x64)
#define STAGE_A(b, h, kt) \
  gld_lds16(&sm[(b)*8192 + ((h)*512 + tid)*8], \
            Abase + (size_t)((h)*64 + sr) * GK + (kt)*64)
#define STAGE_B(b, h, kt) do { \
  gld_lds16(&sm[16384 + (b)*16384 + ((h)*1024 + tid)*8], \
            Bbase + (size_t)((h)*128 + sr) * GK + (kt)*64); \
  gld_lds16(&sm[16384 + (b)*16384 + ((h)*1024 + 512 + tid)*8], \
            Bbase + (size_t)((h)*128 + 64 + sr) * GK + (kt)*64); \
} while (0)

// fragment reads (swizzled): elem = row*64 + colx*8
#define LDA(b, fr, kh) (*(const bf16x8*)&sm[(b)*8192 + rA##fr * 64 + colx##kh * 8])
#define LDB(b, fc, kh) (*(const bf16x8*)&sm[16384 + (b)*16384 + rB##fc * 64 + colx##kh * 8])

#define RDA01(b) do { af[0][0]=LDA(b,0,0); af[0][1]=LDA(b,0,1); \
                      af[1][0]=LDA(b,1,0); af[1][1]=LDA(b,1,1); } while(0)
#define RDA23(b) do { af[2][0]=LDA(b,2,0); af[2][1]=LDA(b,2,1); \
                      af[3][0]=LDA(b,3,0); af[3][1]=LDA(b,3,1); } while(0)
#define RDB01(b) do { bfr[0][0]=LDB(b,0,0); bfr[0][1]=LDB(b,0,1); \
                      bfr[1][0]=LDB(b,1,0); bfr[1][1]=LDB(b,1,1); } while(0)
#define RDB23(b) do { bfr[2][0]=LDB(b,2,0); bfr[2][1]=LDB(b,2,1); \
                      bfr[3][0]=LDB(b,3,0); bfr[3][1]=LDB(b,3,1); } while(0)

#define MFMA1(F, G) do { \
  acc[F][G] = __builtin_amdgcn_mfma_f32_16x16x32_bf16(af[F][0], bfr[G][0], acc[F][G], 0,0,0); \
  acc[F][G] = __builtin_amdgcn_mfma_f32_16x16x32_bf16(af[F][1], bfr[G][1], acc[F][G], 0,0,0); \
} while (0)
#define MQ(F, G) do { __builtin_amdgcn_s_setprio(1); \
  MFMA1(F,G); MFMA1(F,(G)+1); MFMA1((F)+1,G); MFMA1((F)+1,(G)+1); \
  __builtin_amdgcn_s_setprio(0); } while (0)

__global__ __launch_bounds__(512, 2) void gemm8(
    const bf16* __restrict__ A, const bf16* __restrict__ Bt,
    float* __restrict__ C)
{
  __shared__ __align__(16) bf16 sm[49152];   // 96 KiB
  const int tid  = threadIdx.x;
  const int lane = tid & 63, w = tid >> 6;
  const int wm = w >> 2, wn = w & 3;         // 2x4 wave grid
  const int lr = lane & 15, kb = lane >> 4;

  // T1: XCD-aware swizzle (grid=256, 256%8==0): each XCD owns one bn panel.
  int wg  = blockIdx.x;
  int swz = (wg & 7) * 32 + (wg >> 3);
  int bn  = swz >> 5, bm = swz & 31;         // bn 0..7 (N/256), bm 0..31 (M/128)

  // staging thread map: 8 threads per 128B row, T2-swizzled 16B column
  const int sr = tid >> 3;                   // 0..63
  const int sc = (tid & 7) ^ (sr & 7);       // involution: s' = s ^ ((s>>3)&7)
  const bf16* Abase = A  + (size_t)(bm * 128) * GK + sc * 8;
  const bf16* Bbase = Bt + (size_t)(bn * 256) * GK + sc * 8;

  // fragment addressing (read side of the same swizzle)
  const int colx0 = kb ^ (lr & 7);
  const int colx1 = colx0 ^ 4;
  const int rA0 = wm * 32 + lr,        rA1 = rA0 + 16;
  const int rA2 = 64 + wm * 32 + lr,   rA3 = rA2 + 16;
  const int rB0 = wn * 32 + lr,        rB1 = rB0 + 16;
  const int rB2 = 128 + wn * 32 + lr,  rB3 = rB2 + 16;

  f32x4 acc[4][4] = {};
  bf16x8 af[4][2], bfr[4][2];

  // prologue: tile0 full -> buf0 ; tile1 {Bh0, Ah1} -> buf1 (9 loads)
  STAGE_A(0, 0, 0); STAGE_A(0, 1, 0); STAGE_B(0, 0, 0); STAGE_B(0, 1, 0);
  STAGE_B(1, 0, 1); STAGE_A(1, 1, 1);
  VMC(3); BARS();

  for (int i = 0; i < NITER - 1; ++i) {
    const int t1 = 2 * i + 1, t2 = 2 * i + 2, t3 = 2 * i + 3;
    // p1: compute tile 2i quad(Ah0,Bh0); stage t1.Ah0 -> buf1
    RDA01(0); RDB01(0); STAGE_A(1, 0, t1);
    BARS(); MQ(0, 0); BARS();
    // p2: quad(Ah1,Bh0); stage t1.Bh1 -> buf1
    RDA23(0); STAGE_B(1, 1, t1);
    BARS(); MQ(2, 0); BARS();
    // p3: quad(Ah1,Bh1); stage t2.Bh0 -> buf0 (Bh0 freed after p2)
    RDB23(0); STAGE_B(0, 0, t2);
    BARS(); MQ(2, 2); BARS();
    // p4: quad(Ah0,Bh1); stage t2.Ah1 -> buf0 (freed after p3); wait tile t1
    STAGE_A(0, 1, t2);
    VMC(3); BARS(); MQ(0, 2); BARS();
    // p5: compute tile 2i+1 quad(Ah0,Bh0) from buf1; stage t2.Ah0 -> buf0
    RDA01(1); RDB01(1); STAGE_A(0, 0, t2);
    BARS(); MQ(0, 0); BARS();
    // p6: stage t2.Bh1 -> buf0
    RDA23(1); STAGE_B(0, 1, t2);
    BARS(); MQ(2, 0); BARS();
    // p7: stage t3.Bh0 -> buf1 (freed after p6)
    RDB23(1); STAGE_B(1, 0, t3);
    BARS(); MQ(2, 2); BARS();
    // p8: stage t3.Ah1 -> buf1 (freed after p7); wait tile t2
    STAGE_A(1, 1, t3);
    VMC(3); BARS(); MQ(0, 2); BARS();
  }
  // epilogue iteration: tiles 30 (buf0), 31 (buf1); only t31.{Ah0,Bh1} left to stage
  RDA01(0); RDB01(0); STAGE_A(1, 0, NTILE - 1);
  BARS(); MQ(0, 0); BARS();
  RDA23(0); STAGE_B(1, 1, NTILE - 1);
  BARS(); MQ(2, 0); BARS();
  RDB23(0);
  BARS(); MQ(2, 2); BARS();
  VMC(0); BARS(); MQ(0, 2); BARS();
  RDA01(1); RDB01(1);
  BARS(); MQ(0, 0); BARS();
  RDA23(1);
  BARS(); MQ(2, 0); BARS();
  RDB23(1);
  BARS(); MQ(2, 2); BARS();
  MQ(0, 2);

  // epilogue C-write: frag (fr,fc): row = bm*128+(fr>>1)*64+wm*32+(fr&1)*16+kb*4+j
#pragma unroll
  for (int fr = 0; fr < 4; ++fr)
#pragma unroll
    for (int fc = 0; fc < 4; ++fc) {
      size_t r0 = (size_t)(bm * 128) + (fr >> 1) * 64 + wm * 32 + (fr & 1) * 16 + kb * 4;
      int    c0 = bn * 256 + (fc >> 1) * 128 + wn * 32 + (fc & 1) * 16 + lr;
#pragma unroll
      for (int j = 0; j < 4; ++j)
        C[(r0 + j) * C_DIM + c0] = acc[fr][fc][j];
    }
}

// ---------------------------------------------------------------------------
// WKV chunked scan.  Per channel c: decay-per-step D = exp(-f), f = exp(-exp(td)).
__global__ __launch_bounds__(256) void wkv_phase1(
    const float* __restrict__ k, const float* __restrict__ v,
    const float* __restrict__ td,
    float* __restrict__ SA, float* __restrict__ SB)
{
  int c = blockIdx.x * 256 + threadIdx.x;
  int m = blockIdx.y;
  float f = __expf(-__expf(td[c]));
  float D = __expf(-f);
  float sa = 0.f, sb = 0.f;
  size_t base = (size_t)m * CHUNK * C_DIM + c;
  for (int t = 0; t < CHUNK; ++t) {
    float ek = __expf(k[base + (size_t)t * C_DIM]);
    float vv = v[base + (size_t)t * C_DIM];
    sa = D * sa + ek * vv;
    sb = D * sb + ek;
  }
  SA[(size_t)m * C_DIM + c] = sa;
  SB[(size_t)m * C_DIM + c] = sb;
}

__global__ __launch_bounds__(256) void wkv_phase2(
    const float* __restrict__ td,
    const float* __restrict__ SA, const float* __restrict__ SB,
    float* __restrict__ A0, float* __restrict__ B0)
{
  int c = blockIdx.x * 256 + threadIdx.x;
  float f  = __expf(-__expf(td[c]));
  float DL = __expf(-f * (float)CHUNK);
  float a = 0.f, b = 0.f;
  for (int m = 0; m < NCHUNK; ++m) {
    A0[(size_t)m * C_DIM + c] = a;
    B0[(size_t)m * C_DIM + c] = b;
    a = DL * a + SA[(size_t)m * C_DIM + c];
    b = DL * b + SB[(size_t)m * C_DIM + c];
  }
}

__global__ __launch_bounds__(256) void wkv_phase3(
    const float* __restrict__ k, const float* __restrict__ v,
    const float* __restrict__ r,
    const float* __restrict__ td, const float* __restrict__ tf,
    const float* __restrict__ A0, const float* __restrict__ B0,
    bf16* __restrict__ y)
{
  int c = blockIdx.x * 256 + threadIdx.x;
  int m = blockIdx.y;
  float f  = __expf(-__expf(td[c]));
  float D  = __expf(-f);
  float eu = __expf(tf[c]);
  float a = A0[(size_t)m * C_DIM + c];
  float b = B0[(size_t)m * C_DIM + c];
  size_t base = (size_t)m * CHUNK * C_DIM + c;
  for (int t = 0; t < CHUNK; ++t) {
    size_t idx = base + (size_t)t * C_DIM;
    float kk = k[idx], vv = v[idx], rr = r[idx];
    float ek  = __expf(kk);
    float euk = eu * ek;
    float wkv = (a + euk * vv) / (b + euk);
    float sr  = 1.0f / (1.0f + __expf(-rr));
    y[idx] = (bf16)(sr * wkv);
    a = D * a + ek * vv;
    b = D * b + ek;
  }
}

// ---------------------------------------------------------------------------
extern "C" void kernel_launch(void* const* d_in, const int* in_sizes, int n_in,
                              void* d_out, int out_size, void* d_ws, size_t ws_size,
                              hipStream_t stream)
{
  (void)in_sizes; (void)n_in; (void)out_size; (void)ws_size;
  const float* x   = (const float*)d_in[0];
  const float* tf  = (const float*)d_in[1];
  const float* td  = (const float*)d_in[2];
  const float* tmk = (const float*)d_in[3];
  const float* tmv = (const float*)d_in[4];
  const float* tmr = (const float*)d_in[5];
  const float* Wk  = (const float*)d_in[6];
  const float* Wv  = (const float*)d_in[7];
  const float* Wr  = (const float*)d_in[8];
  const float* Wo  = (const float*)d_in[9];
  float* out = (float*)d_out;

  char* ws = (char*)d_ws;
  size_t off = 0;
  auto alloc = [&](size_t bytes) {
    void* p = ws + off;
    off += (bytes + 255) & ~(size_t)255;
    return p;
  };
  const size_t TN  = (size_t)T_LEN * NE_DIM;   // 8,388,608
  const size_t WN  = (size_t)C_DIM * NE_DIM;   // 4,194,304

  bf16* xk  = (bf16*)alloc(TN * 2);
  bf16* xv  = (bf16*)alloc(TN * 2);
  bf16* xr  = (bf16*)alloc(TN * 2);
  bf16* WkT = (bf16*)alloc(WN * 2);
  bf16* WvT = (bf16*)alloc(WN * 2);
  bf16* WrT = (bf16*)alloc(WN * 2);
  bf16* WoT = (bf16*)alloc(WN * 2);
  float* kb = (float*)alloc(TN * 4);
  float* vb = (float*)alloc(TN * 4);
  float* rb = (float*)alloc(TN * 4);
  // Aliases into dead regions (stream-ordered; xk/xv dead after the k/v/r GEMMs):
  bf16*  y  = xk;                              // [T,C] bf16
  float* SA = (float*)xv;
  float* SB = SA + (size_t)NCHUNK * C_DIM;
  float* A0 = SB + (size_t)NCHUNK * C_DIM;
  float* B0 = A0 + (size_t)NCHUNK * C_DIM;

  // 1. mix + bf16 cast
  mix_kernel<<<dim3((unsigned)(TN / 4 / 256)), 256, 0, stream>>>(
      x, tmk, tmv, tmr, xk, xv, xr);
  // 2. weight transpose + bf16 cast
  wtrans<<<dim3(64, 64, 4), dim3(32, 8), 0, stream>>>(
      Wk, Wv, Wr, Wo, WkT, WvT, WrT, WoT);
  // 3. k/v/r projections (8-phase GEMM, grid 256 = 32 M-tiles x 8 N-tiles)
  gemm8<<<dim3(256), 512, 0, stream>>>(xk, WkT, kb);
  gemm8<<<dim3(256), 512, 0, stream>>>(xv, WvT, vb);
  gemm8<<<dim3(256), 512, 0, stream>>>(xr, WrT, rb);
  // 4. WKV chunked scan + sigmoid fuse -> y (bf16)
  wkv_phase1<<<dim3(C_DIM / 256, NCHUNK), 256, 0, stream>>>(kb, vb, td, SA, SB);
  wkv_phase2<<<dim3(C_DIM / 256), 256, 0, stream>>>(td, SA, SB, A0, B0);
  wkv_phase3<<<dim3(C_DIM / 256, NCHUNK), 256, 0, stream>>>(
      kb, vb, rb, td, tf, A0, B0, y);
  // 5. output projection
  gemm8<<<dim3(256), 512, 0, stream>>>(y, WoT, out);
}